// Round 6
// baseline (1026.851 us; speedup 1.0000x reference)
//
#include <hip/hip_runtime.h>

// PyramidPooling: 8 graphs, D=256 fp32 features, stable descending counting
// sort by degree (bins 0..99), then pyramid mean-pool over rank ranges for
// levels {1,2,4,8,16}. Output: out[g*7936 + d*31 + slot], fp32.
//
// v6: pool streams x in MEMORY order (full sequential BW) and routes each
// row to its 5 pool slots via a packed per-node slot word (computed in
// k_scatter from the stable rank). Per-block 31x256 LDS accumulator,
// ds_add_f32 row scatter, coalesced global-atomic flush.

#define DFEAT 256
#define NPOOL 31

// graph node offsets (cumsum of COUNTS)
static __device__ __constant__ int c_goff[9] =
    {0, 12000, 30000, 55000, 70000, 100000, 122000, 139000, 160000};
// 256-node chunk offsets per graph (ceil(n/256) cumsum)
static __device__ __constant__ int c_poff[9] =
    {0, 47, 118, 216, 275, 393, 479, 546, 629};
static __device__ __constant__ int c_lvl[5]    = {1, 2, 4, 8, 16};

#define NCHUNK 629   // 256-node chunks

// Per-chunk histogram (256 nodes, 4 waves; per-wave ballots + LDS combine).
// Blocks 0..247 also zero the acc buffer (folds the memset node).
__global__ __launch_bounds__(256) void k_hist(const int* __restrict__ deg,
                                              int* __restrict__ chist,
                                              float* __restrict__ accb) {
    __shared__ int whist[4][100];
    int c = blockIdx.x;
    int t = threadIdx.x;
    if (c < 248) accb[c * 256 + t] = 0.0f;
    int w = t >> 6, l = t & 63;
    int g = 0;
    while (c >= c_poff[g + 1]) ++g;
    int i = c_goff[g] + (c - c_poff[g]) * 256 + t;
    int bin = -1;
    if (i < c_goff[g + 1]) {
        int dg = deg[i];
        bin = dg < 0 ? 0 : (dg > 99 ? 99 : dg);
    }
    int cnt0 = 0, cnt1 = 0;
    for (int v = 0; v < 100; ++v) {
        unsigned long long m = __ballot(bin == v);
        int pc = __popcll(m);
        if (l == v) cnt0 = pc;
        if (l + 64 == v) cnt1 = pc;
    }
    whist[w][l] = cnt0;
    if (l < 36) whist[w][64 + l] = cnt1;
    __syncthreads();
    if (t < 100)
        chist[c * 100 + t] = whist[0][t] + whist[1][t] + whist[2][t] + whist[3][t];
}

// One wave per (graph, bin): exclusive scan over that graph's chunk counts
// (<=118 chunks -> <=2 iterations), in place; writes bin totals.
__global__ __launch_bounds__(64) void k_scan(int* __restrict__ chist,
                                             int* __restrict__ totals) {
    int b = blockIdx.x;
    int g = b / 100, k = b % 100;
    int l = threadIdx.x;
    int c0 = c_poff[g], c1 = c_poff[g + 1];
    int running = 0;
    for (int base = c0; base < c1; base += 64) {
        int c = base + l;
        int val = (c < c1) ? chist[c * 100 + k] : 0;
        int incl = val;
        #pragma unroll
        for (int off = 1; off < 64; off <<= 1) {
            int y = __shfl_up(incl, off);
            if (l >= off) incl += y;
        }
        if (c < c1) chist[c * 100 + k] = running + (incl - val);
        running += __shfl(incl, 63);
    }
    if (l == 0) totals[g * 100 + k] = running;
}

// Stable rank (256-node chunks): rank = suffix-sum start (descending) +
// chunk base + cross-wave prefix + lanes-below. Emits packed slot word:
// levels {2,4,8,16} -> 5-bit slot ids (level 1 is always slot 0).
__global__ __launch_bounds__(256) void k_scatter(const int* __restrict__ deg,
                                                 const int* __restrict__ chist,
                                                 const int* __restrict__ totals,
                                                 unsigned* __restrict__ slots) {
    __shared__ int tt[100];
    __shared__ int ssum[100];
    __shared__ int whist[4][100];
    int c = blockIdx.x;
    int t = threadIdx.x;
    int w = t >> 6, l = t & 63;
    int g = 0;
    while (c >= c_poff[g + 1]) ++g;

    if (t < 100) tt[t] = totals[g * 100 + t];
    __syncthreads();
    if (t < 100) {
        int s = 0;
        for (int j2 = t + 1; j2 < 100; ++j2) s += tt[j2];
        ssum[t] = s;
    }

    int i = c_goff[g] + (c - c_poff[g]) * 256 + t;
    bool valid = i < c_goff[g + 1];
    int bin = -1;
    if (valid) {
        int dg = deg[i];
        bin = dg < 0 ? 0 : (dg > 99 ? 99 : dg);
    }
    unsigned long long mymask = 0;
    int cnt0 = 0, cnt1 = 0;
    for (int v = 0; v < 100; ++v) {
        unsigned long long m = __ballot(bin == v);
        int pc = __popcll(m);
        if (bin == v) mymask = m;
        if (l == v) cnt0 = pc;
        if (l + 64 == v) cnt1 = pc;
    }
    whist[w][l] = cnt0;
    if (l < 36) whist[w][64 + l] = cnt1;
    __syncthreads();

    if (valid) {
        int wpre = 0;
        for (int w2 = 0; w2 < 4; ++w2)
            if (w2 < w) wpre += whist[w2][bin];
        unsigned long long below = mymask & ((1ull << l) - 1ull);
        int rank = ssum[bin] + chist[c * 100 + bin] + wpre + __popcll(below);
        int nn = c_goff[g + 1] - c_goff[g];
        int kk2  = (nn + 1) >> 1;
        int kk4  = (nn + 3) >> 2;
        int kk8  = (nn + 7) >> 3;
        int kk16 = (nn + 15) >> 4;
        unsigned s2  = 1u  + (unsigned)(rank / kk2);
        unsigned s4  = 3u  + (unsigned)(rank / kk4);
        unsigned s8  = 7u  + (unsigned)(rank / kk8);
        unsigned s16 = 15u + (unsigned)(rank / kk16);
        slots[i] = s2 | (s4 << 5) | (s8 << 10) | (s16 << 15);  // coalesced by i
    }
}

// Pool v6: block = 256 consecutive NODES in memory order (629 blocks).
// Wave w streams rows w, w+4, ... ; lane l loads dims l, l+64, l+128, l+192
// (4x coalesced 256B loads). Row value routed to 4 LDS slots via ds_add_f32
// (level-1 accumulated in registers). Flush: 31 coalesced global atomics.
// All chunk sizes are multiples of 8 -> clean 2-row unroll, no tail.
__global__ __launch_bounds__(256) void k_pool(const float* __restrict__ x,
                                              const unsigned* __restrict__ slots,
                                              float* __restrict__ acc) {
    __shared__ float accL[NPOOL * 256];
    __shared__ unsigned slotSm[256];
    int b = blockIdx.x;
    int g = 0;
    while (b >= c_poff[g + 1]) ++g;
    int n = c_goff[g + 1] - c_goff[g];
    int i0 = c_goff[g] + (b - c_poff[g]) * 256;
    int nrow = min(256, c_goff[g + 1] - i0);
    int t = threadIdx.x;
    #pragma unroll
    for (int q = 0; q < NPOOL; ++q) accL[q * 256 + t] = 0.0f;
    if (t < nrow) slotSm[t] = slots[i0 + t];
    __syncthreads();

    const int w = t >> 6, l = t & 63;
    float a0 = 0.f, a1 = 0.f, a2 = 0.f, a3 = 0.f;

    for (int r = w; r < nrow; r += 8) {
        const float* xrA = x + (size_t)(i0 + r) * DFEAT;
        const float* xrB = x + (size_t)(i0 + r + 4) * DFEAT;
        float vA0 = xrA[l], vA1 = xrA[l + 64], vA2 = xrA[l + 128], vA3 = xrA[l + 192];
        float vB0 = xrB[l], vB1 = xrB[l + 64], vB2 = xrB[l + 128], vB3 = xrB[l + 192];
        unsigned pkA = slotSm[r];
        unsigned pkB = slotSm[r + 4];

        a0 += vA0; a1 += vA1; a2 += vA2; a3 += vA3;
        {
            int s2  = (int)(pkA & 31u) << 8;
            int s4  = (int)((pkA >> 5) & 31u) << 8;
            int s8  = (int)((pkA >> 10) & 31u) << 8;
            int s16 = (int)((pkA >> 15) & 31u) << 8;
            atomicAdd(&accL[s2  + l], vA0); atomicAdd(&accL[s2  + l + 64], vA1);
            atomicAdd(&accL[s2  + l + 128], vA2); atomicAdd(&accL[s2  + l + 192], vA3);
            atomicAdd(&accL[s4  + l], vA0); atomicAdd(&accL[s4  + l + 64], vA1);
            atomicAdd(&accL[s4  + l + 128], vA2); atomicAdd(&accL[s4  + l + 192], vA3);
            atomicAdd(&accL[s8  + l], vA0); atomicAdd(&accL[s8  + l + 64], vA1);
            atomicAdd(&accL[s8  + l + 128], vA2); atomicAdd(&accL[s8  + l + 192], vA3);
            atomicAdd(&accL[s16 + l], vA0); atomicAdd(&accL[s16 + l + 64], vA1);
            atomicAdd(&accL[s16 + l + 128], vA2); atomicAdd(&accL[s16 + l + 192], vA3);
        }
        a0 += vB0; a1 += vB1; a2 += vB2; a3 += vB3;
        {
            int s2  = (int)(pkB & 31u) << 8;
            int s4  = (int)((pkB >> 5) & 31u) << 8;
            int s8  = (int)((pkB >> 10) & 31u) << 8;
            int s16 = (int)((pkB >> 15) & 31u) << 8;
            atomicAdd(&accL[s2  + l], vB0); atomicAdd(&accL[s2  + l + 64], vB1);
            atomicAdd(&accL[s2  + l + 128], vB2); atomicAdd(&accL[s2  + l + 192], vB3);
            atomicAdd(&accL[s4  + l], vB0); atomicAdd(&accL[s4  + l + 64], vB1);
            atomicAdd(&accL[s4  + l + 128], vB2); atomicAdd(&accL[s4  + l + 192], vB3);
            atomicAdd(&accL[s8  + l], vB0); atomicAdd(&accL[s8  + l + 64], vB1);
            atomicAdd(&accL[s8  + l + 128], vB2); atomicAdd(&accL[s8  + l + 192], vB3);
            atomicAdd(&accL[s16 + l], vB0); atomicAdd(&accL[s16 + l + 64], vB1);
            atomicAdd(&accL[s16 + l + 128], vB2); atomicAdd(&accL[s16 + l + 192], vB3);
        }
    }
    // level-1 (slot 0) register accumulators
    atomicAdd(&accL[l], a0);
    atomicAdd(&accL[l + 64], a1);
    atomicAdd(&accL[l + 128], a2);
    atomicAdd(&accL[l + 192], a3);
    __syncthreads();

    float invk[5];
    #pragma unroll
    for (int lev = 0; lev < 5; ++lev)
        invk[lev] = 1.0f / (float)((n + c_lvl[lev] - 1) / c_lvl[lev]);
    float* ag = acc + (size_t)g * (DFEAT * NPOOL);
    #pragma unroll
    for (int slot = 0; slot < NPOOL; ++slot) {
        int lev = (slot == 0) ? 0 : (slot < 3) ? 1 : (slot < 7) ? 2 : (slot < 15) ? 3 : 4;
        atomicAdd(ag + slot * DFEAT + t, accL[slot * 256 + t] * invk[lev]);
    }
}

// Transpose acc[g][slot][d] -> out[g][d][slot].
__global__ __launch_bounds__(256) void k_finish(const float* __restrict__ acc,
                                                float* __restrict__ out, int nOut) {
    int i = blockIdx.x * 256 + threadIdx.x;
    if (i < nOut) {
        int g = i / (DFEAT * NPOOL);
        int rem = i % (DFEAT * NPOOL);
        int d = rem / NPOOL;
        int slot = rem % NPOOL;
        out[i] = acc[g * (DFEAT * NPOOL) + slot * DFEAT + d];
    }
}

extern "C" void kernel_launch(void* const* d_in, const int* in_sizes, int n_in,
                              void* d_out, int out_size, void* d_ws, size_t ws_size,
                              hipStream_t stream) {
    const float* x  = (const float*)d_in[0];
    const int* deg  = (const int*)d_in[2];
    float* out      = (float*)d_out;

    int* ws          = (int*)d_ws;
    int* chist       = ws;                    // NCHUNK*100 = 62900 ints
    int* totals      = ws + 62900;            // 800 ints
    unsigned* slots  = (unsigned*)(ws + 63700);  // 160000 u32
    float* accb      = (float*)(ws + 223700); // 63488 floats (~1.15 MB total ws)

    hipLaunchKernelGGL(k_hist, dim3(NCHUNK), dim3(256), 0, stream, deg, chist, accb);
    hipLaunchKernelGGL(k_scan, dim3(800), dim3(64), 0, stream, chist, totals);
    hipLaunchKernelGGL(k_scatter, dim3(NCHUNK), dim3(256), 0, stream, deg, chist,
                       totals, slots);
    hipLaunchKernelGGL(k_pool, dim3(NCHUNK), dim3(256), 0, stream, x, slots, accb);
    hipLaunchKernelGGL(k_finish, dim3((out_size + 255) / 256), dim3(256), 0, stream,
                       accb, out, out_size);
}

// Round 7
// 79.264 us; speedup vs baseline: 12.9549x; 12.9549x over previous
//
#include <hip/hip_runtime.h>

// PyramidPooling: 8 graphs, D=256 fp32 features, stable descending counting
// sort by degree (bins 0..99), then pyramid mean-pool over rank ranges for
// levels {1,2,4,8,16}. Output: out[g*7936 + d*31 + slot], fp32.
//
// v7: pool streams x in MEMORY order (sequential BW). Each node carries a
// 5-bit SEGMENT id (partition induced by union of all level boundaries,
// seg = sum of per-level slot indices, <=27 segs). Thread t owns dim t and a
// private 27-float LDS column -> plain ds read/add/write, NO atomics in the
// hot loop (LDS atomicAdd is ~serial on CDNA4 — round-6 lesson: 1 ms!).
// Flush decodes segments->slots by walking boundaries; coalesced global
// atomics into acc[g][slot][d].

#define DFEAT 256
#define NPOOL 31

// graph node offsets (cumsum of COUNTS)
static __device__ __constant__ int c_goff[9] =
    {0, 12000, 30000, 55000, 70000, 100000, 122000, 139000, 160000};
// 256-node chunk offsets per graph (ceil(n/256) cumsum)
static __device__ __constant__ int c_poff[9] =
    {0, 47, 118, 216, 275, 393, 479, 546, 629};

#define NCHUNK 629   // 256-node chunks

// Per-chunk histogram (256 nodes, 4 waves; per-wave ballots + LDS combine).
// Blocks 0..247 also zero the acc buffer (folds the memset node).
__global__ __launch_bounds__(256) void k_hist(const int* __restrict__ deg,
                                              int* __restrict__ chist,
                                              float* __restrict__ accb) {
    __shared__ int whist[4][100];
    int c = blockIdx.x;
    int t = threadIdx.x;
    if (c < 248) accb[c * 256 + t] = 0.0f;
    int w = t >> 6, l = t & 63;
    int g = 0;
    while (c >= c_poff[g + 1]) ++g;
    int i = c_goff[g] + (c - c_poff[g]) * 256 + t;
    int bin = -1;
    if (i < c_goff[g + 1]) {
        int dg = deg[i];
        bin = dg < 0 ? 0 : (dg > 99 ? 99 : dg);
    }
    int cnt0 = 0, cnt1 = 0;
    for (int v = 0; v < 100; ++v) {
        unsigned long long m = __ballot(bin == v);
        int pc = __popcll(m);
        if (l == v) cnt0 = pc;
        if (l + 64 == v) cnt1 = pc;
    }
    whist[w][l] = cnt0;
    if (l < 36) whist[w][64 + l] = cnt1;
    __syncthreads();
    if (t < 100)
        chist[c * 100 + t] = whist[0][t] + whist[1][t] + whist[2][t] + whist[3][t];
}

// One wave per (graph, bin): exclusive scan over that graph's chunk counts
// (<=118 chunks -> <=2 iterations), in place; writes bin totals.
__global__ __launch_bounds__(64) void k_scan(int* __restrict__ chist,
                                             int* __restrict__ totals) {
    int b = blockIdx.x;
    int g = b / 100, k = b % 100;
    int l = threadIdx.x;
    int c0 = c_poff[g], c1 = c_poff[g + 1];
    int running = 0;
    for (int base = c0; base < c1; base += 64) {
        int c = base + l;
        int val = (c < c1) ? chist[c * 100 + k] : 0;
        int incl = val;
        #pragma unroll
        for (int off = 1; off < 64; off <<= 1) {
            int y = __shfl_up(incl, off);
            if (l >= off) incl += y;
        }
        if (c < c1) chist[c * 100 + k] = running + (incl - val);
        running += __shfl(incl, 63);
    }
    if (l == 0) totals[g * 100 + k] = running;
}

// Stable rank (256-node chunks): rank = suffix-sum start (descending) +
// chunk base + cross-wave prefix + lanes-below. Emits SEGMENT id:
// seg = rank/k2 + rank/k4 + rank/k8 + rank/k16  (0..26).
__global__ __launch_bounds__(256) void k_scatter(const int* __restrict__ deg,
                                                 const int* __restrict__ chist,
                                                 const int* __restrict__ totals,
                                                 unsigned* __restrict__ segs) {
    __shared__ int tt[100];
    __shared__ int ssum[100];
    __shared__ int whist[4][100];
    int c = blockIdx.x;
    int t = threadIdx.x;
    int w = t >> 6, l = t & 63;
    int g = 0;
    while (c >= c_poff[g + 1]) ++g;

    if (t < 100) tt[t] = totals[g * 100 + t];
    __syncthreads();
    if (t < 100) {
        int s = 0;
        for (int j2 = t + 1; j2 < 100; ++j2) s += tt[j2];
        ssum[t] = s;
    }

    int i = c_goff[g] + (c - c_poff[g]) * 256 + t;
    bool valid = i < c_goff[g + 1];
    int bin = -1;
    if (valid) {
        int dg = deg[i];
        bin = dg < 0 ? 0 : (dg > 99 ? 99 : dg);
    }
    unsigned long long mymask = 0;
    int cnt0 = 0, cnt1 = 0;
    for (int v = 0; v < 100; ++v) {
        unsigned long long m = __ballot(bin == v);
        int pc = __popcll(m);
        if (bin == v) mymask = m;
        if (l == v) cnt0 = pc;
        if (l + 64 == v) cnt1 = pc;
    }
    whist[w][l] = cnt0;
    if (l < 36) whist[w][64 + l] = cnt1;
    __syncthreads();

    if (valid) {
        int wpre = 0;
        for (int w2 = 0; w2 < 4; ++w2)
            if (w2 < w) wpre += whist[w2][bin];
        unsigned long long below = mymask & ((1ull << l) - 1ull);
        int rank = ssum[bin] + chist[c * 100 + bin] + wpre + __popcll(below);
        int nn = c_goff[g + 1] - c_goff[g];
        int kk2  = (nn + 1) >> 1;
        int kk4  = (nn + 3) >> 2;
        int kk8  = (nn + 7) >> 3;
        int kk16 = (nn + 15) >> 4;
        segs[i] = (unsigned)(rank / kk2 + rank / kk4 + rank / kk8 + rank / kk16);
    }
}

// Pool v7: block = 256 consecutive NODES in memory order (629 blocks).
// Thread t = dim t; private LDS column accP[t*27+seg] (odd stride ->
// bank-conflict-free; seg is wave-uniform per row). Per row: 1 coalesced
// global load + 1 plain LDS RMW. Flush: walk level boundaries, running
// register sums, coalesced global atomics (pre-scaled by 1/kernel).
__global__ __launch_bounds__(256) void k_pool(const float* __restrict__ x,
                                              const unsigned* __restrict__ segs,
                                              float* __restrict__ acc) {
    __shared__ float accP[256 * 27];
    __shared__ unsigned segSm[256];
    int b = blockIdx.x;
    int g = 0;
    while (b >= c_poff[g + 1]) ++g;
    int n = c_goff[g + 1] - c_goff[g];
    int i0 = c_goff[g] + (b - c_poff[g]) * 256;
    int nrow = min(256, c_goff[g + 1] - i0);
    int t = threadIdx.x;
    #pragma unroll
    for (int q = 0; q < 27; ++q) accP[t * 27 + q] = 0.0f;
    if (t < nrow) segSm[t] = segs[i0 + t];
    __syncthreads();

    float* myacc = accP + t * 27;
    const float* xp = x + (size_t)i0 * DFEAT + t;

    #pragma unroll 8
    for (int r = 0; r < nrow; ++r) {
        float v = xp[(size_t)r * DFEAT];
        myacc[segSm[r]] += v;
    }
    __syncthreads();  // not strictly needed (private columns), keeps timing sane

    // ---- flush: walk the boundary-union segments in rank order ----
    int kk2  = (n + 1) >> 1;
    int kk4  = (n + 3) >> 2;
    int kk8  = (n + 7) >> 3;
    int kk16 = (n + 15) >> 4;
    float inv1  = 1.0f / (float)n;
    float inv2  = 1.0f / (float)kk2;
    float inv4  = 1.0f / (float)kk4;
    float inv8  = 1.0f / (float)kk8;
    float inv16 = 1.0f / (float)kk16;
    float* ag = acc + (size_t)g * (DFEAT * NPOOL);

    int j2 = 0, j4 = 0, j8 = 0, j16 = 0;
    float r1 = 0.f, r2 = 0.f, r4 = 0.f, r8 = 0.f, r16 = 0.f;
    int pos = 0;
    while (pos < n) {
        int b2 = (j2 + 1) * kk2, b4 = (j4 + 1) * kk4;
        int b8 = (j8 + 1) * kk8, b16 = (j16 + 1) * kk16;
        int nb = min(n, min(min(b2, b4), min(b8, b16)));
        int seg = j2 + j4 + j8 + j16;
        float a = myacc[seg];
        r1 += a; r2 += a; r4 += a; r8 += a; r16 += a;
        pos = nb;
        if (nb == b16 || nb == n) {
            atomicAdd(ag + (15 + j16) * DFEAT + t, r16 * inv16);
            r16 = 0.f; ++j16;
        }
        if (nb == b8 || nb == n) {
            atomicAdd(ag + (7 + j8) * DFEAT + t, r8 * inv8);
            r8 = 0.f; ++j8;
        }
        if (nb == b4 || nb == n) {
            atomicAdd(ag + (3 + j4) * DFEAT + t, r4 * inv4);
            r4 = 0.f; ++j4;
        }
        if (nb == b2 || nb == n) {
            atomicAdd(ag + (1 + j2) * DFEAT + t, r2 * inv2);
            r2 = 0.f; ++j2;
        }
    }
    atomicAdd(ag + t, r1 * inv1);  // level-1, slot 0
}

// Transpose acc[g][slot][d] -> out[g][d][slot].
__global__ __launch_bounds__(256) void k_finish(const float* __restrict__ acc,
                                                float* __restrict__ out, int nOut) {
    int i = blockIdx.x * 256 + threadIdx.x;
    if (i < nOut) {
        int g = i / (DFEAT * NPOOL);
        int rem = i % (DFEAT * NPOOL);
        int d = rem / NPOOL;
        int slot = rem % NPOOL;
        out[i] = acc[g * (DFEAT * NPOOL) + slot * DFEAT + d];
    }
}

extern "C" void kernel_launch(void* const* d_in, const int* in_sizes, int n_in,
                              void* d_out, int out_size, void* d_ws, size_t ws_size,
                              hipStream_t stream) {
    const float* x  = (const float*)d_in[0];
    const int* deg  = (const int*)d_in[2];
    float* out      = (float*)d_out;

    int* ws          = (int*)d_ws;
    int* chist       = ws;                       // NCHUNK*100 = 62900 ints
    int* totals      = ws + 62900;               // 800 ints
    unsigned* segsW  = (unsigned*)(ws + 63700);  // 160000 u32
    float* accb      = (float*)(ws + 223700);    // 63488 floats (~1.15 MB ws)

    hipLaunchKernelGGL(k_hist, dim3(NCHUNK), dim3(256), 0, stream, deg, chist, accb);
    hipLaunchKernelGGL(k_scan, dim3(800), dim3(64), 0, stream, chist, totals);
    hipLaunchKernelGGL(k_scatter, dim3(NCHUNK), dim3(256), 0, stream, deg, chist,
                       totals, segsW);
    hipLaunchKernelGGL(k_pool, dim3(NCHUNK), dim3(256), 0, stream, x, segsW, accb);
    hipLaunchKernelGGL(k_finish, dim3((out_size + 255) / 256), dim3(256), 0, stream,
                       accb, out, out_size);
}

// Round 8
// 76.196 us; speedup vs baseline: 13.4765x; 1.0403x over previous
//
#include <hip/hip_runtime.h>

// PyramidPooling: 8 graphs, D=256 fp32 features, stable descending counting
// sort by degree (bins 0..99), then pyramid mean-pool over rank ranges for
// levels {1,2,4,8,16}. Output: out[g*7936 + d*31 + slot], fp32.
//
// v8 = round-5 structure minus the k_scan stage: k_scatter re-derives bin
// totals + its own chunk prefix from raw chist (L2-resident, coalesced).
// Pool = proven rank-order gather (random-1KB-granule ceiling ~4.5TB/s;
// memory-order alternatives lose to LDS scatter cost — rounds 6/7).

#define DFEAT 256
#define NPOOL 31

// graph node offsets (cumsum of COUNTS)
static __device__ __constant__ int c_goff[9] =
    {0, 12000, 30000, 55000, 70000, 100000, 122000, 139000, 160000};
// 256-node chunk offsets per graph (ceil(n/256) cumsum)
static __device__ __constant__ int c_poff[9] =
    {0, 47, 118, 216, 275, 393, 479, 546, 629};
static __device__ __constant__ int c_lvl[5]    = {1, 2, 4, 8, 16};
static __device__ __constant__ int c_lvloff[5] = {0, 1, 3, 7, 15};

#define NCHUNK 629   // 256-node chunks

// Per-chunk histogram (256 nodes, 4 waves; per-wave ballots + LDS combine).
// Blocks 0..247 also zero the acc buffer (folds the memset node).
__global__ __launch_bounds__(256) void k_hist(const int* __restrict__ deg,
                                              int* __restrict__ chist,
                                              float* __restrict__ accb) {
    __shared__ int whist[4][100];
    int c = blockIdx.x;
    int t = threadIdx.x;
    if (c < 248) accb[c * 256 + t] = 0.0f;
    int w = t >> 6, l = t & 63;
    int g = 0;
    while (c >= c_poff[g + 1]) ++g;
    int i = c_goff[g] + (c - c_poff[g]) * 256 + t;
    int bin = -1;
    if (i < c_goff[g + 1]) {
        int dg = deg[i];
        bin = dg < 0 ? 0 : (dg > 99 ? 99 : dg);
    }
    int cnt0 = 0, cnt1 = 0;
    for (int v = 0; v < 100; ++v) {
        unsigned long long m = __ballot(bin == v);
        int pc = __popcll(m);
        if (l == v) cnt0 = pc;
        if (l + 64 == v) cnt1 = pc;
    }
    whist[w][l] = cnt0;
    if (l < 36) whist[w][64 + l] = cnt1;
    __syncthreads();
    if (t < 100)
        chist[c * 100 + t] = whist[0][t] + whist[1][t] + whist[2][t] + whist[3][t];
}

// Stable scatter, scan fused: thread t<100 sums chist over the graph's
// chunks (coalesced 400B rows, L2-resident) -> totals + this-chunk prefix.
// rank = suffix-sum start (descending) + chunk base + cross-wave prefix
// (ballot hist in LDS) + same-bin-lanes-below.
__global__ __launch_bounds__(256) void k_scatter(const int* __restrict__ deg,
                                                 const int* __restrict__ chist,
                                                 int* __restrict__ sidx) {
    __shared__ int tot[100];
    __shared__ int basev[100];
    __shared__ int ssum[100];
    __shared__ int whist[4][100];
    int c = blockIdx.x;
    int t = threadIdx.x;
    int w = t >> 6, l = t & 63;
    int g = 0;
    while (c >= c_poff[g + 1]) ++g;
    int c0 = c_poff[g], c1 = c_poff[g + 1];

    if (t < 100) {
        int total = 0, base = 0;
        for (int cc = c0; cc < c1; ++cc) {
            int v = chist[cc * 100 + t];
            total += v;
            if (cc < c) base += v;
        }
        tot[t] = total;
        basev[t] = base;
    }
    __syncthreads();
    if (t < 100) {
        int s = 0;
        for (int j2 = t + 1; j2 < 100; ++j2) s += tot[j2];
        ssum[t] = s;
    }

    int i = c_goff[g] + (c - c_poff[g]) * 256 + t;
    bool valid = i < c_goff[g + 1];
    int bin = -1;
    if (valid) {
        int dg = deg[i];
        bin = dg < 0 ? 0 : (dg > 99 ? 99 : dg);
    }
    unsigned long long mymask = 0;
    int cnt0 = 0, cnt1 = 0;
    for (int v = 0; v < 100; ++v) {
        unsigned long long m = __ballot(bin == v);
        int pc = __popcll(m);
        if (bin == v) mymask = m;
        if (l == v) cnt0 = pc;
        if (l + 64 == v) cnt1 = pc;
    }
    whist[w][l] = cnt0;
    if (l < 36) whist[w][64 + l] = cnt1;
    __syncthreads();

    if (valid) {
        int wpre = 0;
        for (int w2 = 0; w2 < 4; ++w2)
            if (w2 < w) wpre += whist[w2][bin];
        unsigned long long below = mymask & ((1ull << l) - 1ull);
        int rank = ssum[bin] + basev[bin] + wpre + __popcll(below);
        sidx[c_goff[g] + rank] = i;  // global node index
    }
}

// Pool (round-5 proven form): block = 256 consecutive ranks (629 blocks).
// Wave w handles rows s+w, +4, ...; lane loads float4 (64 lanes = full 1KB
// row), 4 independent loads in flight. Segment = boundary-free row range:
// sum once, flush S*invk to all 5 levels via coalesced atomics into
// acc[g][slot][d] (slot-major, L2-resident).
__global__ __launch_bounds__(256) void k_pool(const float* __restrict__ x,
                                              const int* __restrict__ sidx,
                                              float* __restrict__ acc) {
    __shared__ int sIdxSm[256];
    __shared__ float red[1024];
    int b = blockIdx.x;
    int g = 0;
    while (b >= c_poff[g + 1]) ++g;
    int n = c_goff[g + 1] - c_goff[g];
    int r0 = (b - c_poff[g]) * 256;
    int r1 = min(r0 + 256, n);
    int t = threadIdx.x;
    if (t < r1 - r0) sIdxSm[t] = sidx[c_goff[g] + r0 + t];
    __syncthreads();

    const int w = t >> 6;
    const int l = t & 63;

    float invk[5];
    int j[5], nb[5], kk[5];
    #pragma unroll
    for (int lev = 0; lev < 5; ++lev) {
        int p = c_lvl[lev];
        kk[lev] = (n + p - 1) / p;
        invk[lev] = 1.0f / (float)kk[lev];
        j[lev] = r0 / kk[lev];
        nb[lev] = (j[lev] + 1) * kk[lev];
    }
    float* ag = acc + (size_t)g * (DFEAT * NPOOL);

    int s = r0;
    while (s < r1) {
        int send = r1;
        #pragma unroll
        for (int lev = 0; lev < 5; ++lev) send = min(send, nb[lev]);

        float4 a0 = {0, 0, 0, 0}, a1 = {0, 0, 0, 0};
        float4 a2 = {0, 0, 0, 0}, a3 = {0, 0, 0, 0};
        int r = s + w;
        for (; r + 12 < send; r += 16) {
            const float4 v0 = *(const float4*)(x + (size_t)sIdxSm[r      - r0] * DFEAT + l * 4);
            const float4 v1 = *(const float4*)(x + (size_t)sIdxSm[r + 4  - r0] * DFEAT + l * 4);
            const float4 v2 = *(const float4*)(x + (size_t)sIdxSm[r + 8  - r0] * DFEAT + l * 4);
            const float4 v3 = *(const float4*)(x + (size_t)sIdxSm[r + 12 - r0] * DFEAT + l * 4);
            a0 += v0; a1 += v1; a2 += v2; a3 += v3;
        }
        for (; r < send; r += 4) {
            a0 += *(const float4*)(x + (size_t)sIdxSm[r - r0] * DFEAT + l * 4);
        }
        a0 += a1; a2 += a3; a0 += a2;
        *(float4*)(red + w * 256 + l * 4) = a0;
        __syncthreads();
        float S = red[t] + red[256 + t] + red[512 + t] + red[768 + t];
        #pragma unroll
        for (int lev = 0; lev < 5; ++lev) {
            atomicAdd(ag + (c_lvloff[lev] + j[lev]) * DFEAT + t, S * invk[lev]);
            if (send == nb[lev]) { j[lev]++; nb[lev] += kk[lev]; }
        }
        s = send;
        __syncthreads();
    }
}

// Transpose acc[g][slot][d] -> out[g][d][slot].
__global__ __launch_bounds__(256) void k_finish(const float* __restrict__ acc,
                                                float* __restrict__ out, int nOut) {
    int i = blockIdx.x * 256 + threadIdx.x;
    if (i < nOut) {
        int g = i / (DFEAT * NPOOL);
        int rem = i % (DFEAT * NPOOL);
        int d = rem / NPOOL;
        int slot = rem % NPOOL;
        out[i] = acc[g * (DFEAT * NPOOL) + slot * DFEAT + d];
    }
}

extern "C" void kernel_launch(void* const* d_in, const int* in_sizes, int n_in,
                              void* d_out, int out_size, void* d_ws, size_t ws_size,
                              hipStream_t stream) {
    const float* x  = (const float*)d_in[0];
    const int* deg  = (const int*)d_in[2];
    float* out      = (float*)d_out;

    int* ws      = (int*)d_ws;
    int* chist   = ws;                     // NCHUNK*100 = 62900 ints
    int* sidx    = ws + 63700;             // 160000 ints
    float* accb  = (float*)(ws + 223700);  // 63488 floats (~1.15 MB total ws)

    hipLaunchKernelGGL(k_hist, dim3(NCHUNK), dim3(256), 0, stream, deg, chist, accb);
    hipLaunchKernelGGL(k_scatter, dim3(NCHUNK), dim3(256), 0, stream, deg, chist,
                       sidx);
    hipLaunchKernelGGL(k_pool, dim3(NCHUNK), dim3(256), 0, stream, x, sidx, accb);
    hipLaunchKernelGGL(k_finish, dim3((out_size + 255) / 256), dim3(256), 0, stream,
                       accb, out, out_size);
}